// Round 15
// baseline (52.388 us; speedup 1.0000x reference)
//
#include <hip/hip_runtime.h>
#include <math.h>

#define HW_ 1024

typedef __attribute__((ext_vector_type(4))) float   f32x4;
typedef __attribute__((ext_vector_type(8))) short   s16x8;
typedef s16x8 __attribute__((may_alias)) s16x8_a;

__device__ __forceinline__ unsigned bf16rne(float x) {
  unsigned u = __builtin_bit_cast(unsigned, x);
  u += 0x7FFF + ((u >> 16) & 1);
  return u >> 16;
}
__device__ __forceinline__ float bf2f(ushort u) {
  return __builtin_bit_cast(float, (unsigned)u << 16);
}

__device__ __forceinline__ void store_oc(int oc, const float av[4],
    float* __restrict__ out, ushort* __restrict__ qbf, ushort* __restrict__ kbf,
    ushort* __restrict__ vtg, int b, int p)
{
  if (oc < 64) {
    float4 acc = make_float4(av[0], av[1], av[2], av[3]);
    *(float4*)(out + ((size_t)b * 128 + oc) * HW_ + p) = acc;
  } else if (oc < 128) {
    const float SC = 0.35355339059327373f * 1.4426950408889634f;  // dkh^-0.5 * log2e
    int qc = oc - 64, n = qc >> 3, d = qc & 7, bn = b * 8 + n;
    #pragma unroll
    for (int i = 0; i < 4; ++i)
      qbf[((size_t)bn * HW_ + p + i) * 8 + d] = (ushort)bf16rne(av[i] * SC);
  } else if (oc < 192) {
    int kc = oc - 128, n = kc >> 3, d = kc & 7, bn = b * 8 + n;
    #pragma unroll
    for (int i = 0; i < 4; ++i)
      kbf[((size_t)bn * HW_ + p + i) * 8 + d] = (ushort)bf16rne(av[i]);
  } else {
    int vc = oc - 192, n = vc >> 3, d = vc & 7, bn = b * 8 + n;
    #pragma unroll
    for (int i = 0; i < 4; ++i)
      vtg[((size_t)bn * 8 + d) * HW_ + p + i] = (ushort)bf16rne(av[i]);
  }
}

// ---------------- K1: fused 1x1 convs, 2 oc/thread (R11-proven) ----------------
// grid 512 = b(4) x ocp(32) x pt(4); 256 thr; thread: oc0=ocp*8+(tid>>6)*2, oc0+1
__global__ __launch_bounds__(256) void k_convs(
    const float* __restrict__ x, const float* __restrict__ w_conv, const float* __restrict__ b_conv,
    const float* __restrict__ w_qkv, const float* __restrict__ b_qkv,
    float* __restrict__ out,
    ushort* __restrict__ qbf, ushort* __restrict__ kbf, ushort* __restrict__ vtg)
{
  int bid = blockIdx.x;
  int pt  = bid & 3;
  int ocp = (bid >> 2) & 31;
  int b   = bid >> 7;
  int tid = threadIdx.x;
  int oc0 = ocp * 8 + (tid >> 6) * 2;      // even; pair stays within region
  int oc1 = oc0 + 1;
  int p   = pt * 256 + (tid & 63) * 4;

  const float* wrow0; const float* wrow1;
  float bias0, bias1;
  if (oc0 < 64) { wrow0 = w_conv + oc0 * 64; bias0 = b_conv[oc0];
                  wrow1 = w_conv + oc1 * 64; bias1 = b_conv[oc1]; }
  else          { wrow0 = w_qkv + (oc0 - 64) * 64; bias0 = b_qkv[oc0 - 64];
                  wrow1 = w_qkv + (oc1 - 64) * 64; bias1 = b_qkv[oc1 - 64]; }

  float4 a00 = make_float4(bias0, bias0, bias0, bias0);
  float4 a01 = make_float4(0.f, 0.f, 0.f, 0.f);
  float4 a10 = make_float4(bias1, bias1, bias1, bias1);
  float4 a11 = make_float4(0.f, 0.f, 0.f, 0.f);
  const float* xb = x + (size_t)b * 64 * HW_ + p;
  #pragma unroll 16
  for (int ci = 0; ci < 32; ++ci) {
    float4 x0 = *(const float4*)(xb + (size_t)ci * HW_);
    float4 x1 = *(const float4*)(xb + (size_t)(ci + 32) * HW_);
    float w00 = wrow0[ci], w01 = wrow0[ci + 32];
    float w10 = wrow1[ci], w11 = wrow1[ci + 32];
    a00.x = fmaf(w00, x0.x, a00.x); a01.x = fmaf(w01, x1.x, a01.x);
    a00.y = fmaf(w00, x0.y, a00.y); a01.y = fmaf(w01, x1.y, a01.y);
    a00.z = fmaf(w00, x0.z, a00.z); a01.z = fmaf(w01, x1.z, a01.z);
    a00.w = fmaf(w00, x0.w, a00.w); a01.w = fmaf(w01, x1.w, a01.w);
    a10.x = fmaf(w10, x0.x, a10.x); a11.x = fmaf(w11, x1.x, a11.x);
    a10.y = fmaf(w10, x0.y, a10.y); a11.y = fmaf(w11, x1.y, a11.y);
    a10.z = fmaf(w10, x0.z, a10.z); a11.z = fmaf(w11, x1.z, a11.z);
    a10.w = fmaf(w10, x0.w, a10.w); a11.w = fmaf(w11, x1.w, a11.w);
  }
  float av0[4] = {a00.x + a01.x, a00.y + a01.y, a00.z + a01.z, a00.w + a01.w};
  float av1[4] = {a10.x + a11.x, a10.y + a11.y, a10.z + a11.z, a10.w + a11.w};
  store_oc(oc0, av0, out, qbf, kbf, vtg, b, p);
  store_oc(oc1, av1, out, qbf, kbf, vtg, b, p);
}

// ---------------- K2: MFMA flash attention (R14 - V_lds + halved P_lds, 3 blocks/CU) ----------------
// grid 512 = bn(32) x qt(16); 512 thr = 8 waves: qsub(4) x key-half(2)
// wave: 16 q-cols x 512 keys. S^T = mfma(K_lds, Q^T, C=rel); P via per-wave
// halved swizzled LDS (two 64-key rounds/bk); O^T = mfma(V^T(+ones), P^T, O).
__global__ __launch_bounds__(512, 6) void k_attn(
    const ushort* __restrict__ qbf, const ushort* __restrict__ kbf, const ushort* __restrict__ vtg,
    const float* __restrict__ rel_h, const float* __restrict__ rel_w,
    float* __restrict__ aws)
{
  __shared__ ushort rhd[64 * 36];        // bf16, stride 36
  __shared__ ushort rwd[64 * 36];
  __shared__ ushort P_lds[8][16][64];    // per-wave [q][key-of-half], 128B rows, XOR-swizzled
  __shared__ __align__(16) ushort K_lds[1024 * 8];  // whole head's K, [key][d], 16KB
  __shared__ float mbuf[4][16], lbuf[4][16];
  __shared__ float obuf[4][16][8];

  int bid = blockIdx.x;
  int qt = bid & 15;
  int bn = bid >> 4;
  int b = bn >> 3, n = bn & 7;
  int tid = threadIdx.x;
  int lane = tid & 63;
  int w = tid >> 6;
  int qsub = w & 3, half = w >> 2;

  // ---- stage K into LDS (coalesced, 2 keys x 16B per thread)
  {
    const uint4* ksrc = (const uint4*)(kbf + (size_t)bn * HW_ * 8);
    uint4* kdst = (uint4*)K_lds;
    kdst[tid]       = ksrc[tid];
    kdst[tid + 512] = ksrc[tid + 512];
  }

  // ---- build rel tables (bf16): rhd[qr][hp] = q.rel_h[hp-h+31], rwd[qr][wp] = q.rel_w[wp-w+31]
  {
    int qr = tid >> 3, qu = tid & 7;
    const ushort* qp = qbf + ((size_t)bn * HW_ + qt * 64 + qr) * 8;
    float qf[8];
    #pragma unroll
    for (int d = 0; d < 8; ++d) qf[d] = bf2f(qp[d]);
    int h = (qt * 64 + qr) >> 5, ww = qr & 31;
    #pragma unroll
    for (int s = 0; s < 4; ++s) {
      int idx = qu * 4 + s;
      const float* rp = rel_h + (idx - h + 31) * 8;
      float a = 0.f;
      #pragma unroll
      for (int d = 0; d < 8; ++d) a = fmaf(qf[d], rp[d], a);
      rhd[qr * 36 + idx] = (ushort)bf16rne(a);
      const float* rq = rel_w + (idx - ww + 31) * 8;
      float c = 0.f;
      #pragma unroll
      for (int d = 0; d < 8; ++d) c = fmaf(qf[d], rq[d], c);
      rwd[qr * 36 + idx] = (ushort)bf16rne(c);
    }
  }
  __syncthreads();

  int q = lane & 15, g = lane >> 4;
  int qr = qsub * 16 + q;

  s16x8 qfrag = {0,0,0,0,0,0,0,0};
  if (lane < 16)
    qfrag = *(const s16x8*)(qbf + ((size_t)bn * HW_ + qt * 64 + qsub * 16 + lane) * 8);

  float rw2[2][4];
  #pragma unroll
  for (int r = 0; r < 4; ++r) {
    rw2[0][r] = bf2f(rwd[qr * 36 + g * 4 + r]);
    rw2[1][r] = bf2f(rwd[qr * 36 + 16 + g * 4 + r]);
  }

  const ushort* vbase = vtg + (size_t)bn * 8 * HW_;

  s16x8 vone;
  #pragma unroll
  for (int e = 0; e < 8; ++e) vone[e] = (short)0x3F80;   // bf16 1.0
  s16x8 vzero = {0,0,0,0,0,0,0,0};

  float m = -1e30f;
  f32x4 O = {0.f, 0.f, 0.f, 0.f};

  char* prow = (char*)&P_lds[w][0][0] + q * 128;
  int sw = (q & 7) << 4;

  #pragma unroll
  for (int bki = 0; bki < 4; ++bki) {
    int bk = half * 4 + bki;
    float rh4[4];
    #pragma unroll
    for (int j = 0; j < 4; ++j) rh4[j] = bf2f(rhd[qr * 36 + bk * 4 + j]);

    // ---- QK^T (S^T), rel logits as C-init; K from LDS
    f32x4 s[8];
    __builtin_amdgcn_s_setprio(1);
    #pragma unroll
    for (int t = 0; t < 8; ++t) {
      f32x4 c;
      #pragma unroll
      for (int r = 0; r < 4; ++r) c[r] = rh4[t >> 1] + rw2[t & 1][r];
      s16x8 kf = {0,0,0,0,0,0,0,0};
      if (lane < 16)
        kf = *(const s16x8*)(K_lds + (size_t)(bk * 128 + t * 16 + lane) * 8);
      s[t] = __builtin_amdgcn_mfma_f32_16x16x32_bf16(kf, qfrag, c, 0, 0, 0);
    }
    __builtin_amdgcn_s_setprio(0);

    // ---- V fragments for this bk (global, hoisted before pack/fence — R13-proven)
    s16x8 vfr[4];
    #pragma unroll
    for (int km = 0; km < 4; ++km) {
      if (q < 8)      vfr[km] = *(const s16x8*)(vbase + (size_t)q * HW_ + bk * 128 + km * 32 + g * 8);
      else if (q == 8) vfr[km] = vone;
      else             vfr[km] = vzero;
    }

    // ---- online softmax max (base-2 domain)
    float t8[8];
    #pragma unroll
    for (int t = 0; t < 8; ++t)
      t8[t] = fmaxf(fmaxf(s[t][0], s[t][1]), fmaxf(s[t][2], s[t][3]));
    float mx = fmaxf(fmaxf(fmaxf(t8[0], t8[1]), fmaxf(t8[2], t8[3])),
                     fmaxf(fmaxf(t8[4], t8[5]), fmaxf(t8[6], t8[7])));
    mx = fmaxf(mx, __shfl_xor(mx, 16));
    mx = fmaxf(mx, __shfl_xor(mx, 32));
    float mn = fmaxf(m, mx);
    float corr = __builtin_amdgcn_exp2f(m - mn);
    m = mn;

    #pragma unroll
    for (int t = 0; t < 8; ++t)
      #pragma unroll
      for (int r = 0; r < 4; ++r)
        s[t][r] = __builtin_amdgcn_exp2f(s[t][r] - mn);

    #pragma unroll
    for (int r = 0; r < 4; ++r) O[r] *= corr;

    // ---- two 64-key half-rounds: pack 4 t -> fence -> 2 PV MFMAs
    #pragma unroll
    for (int hh = 0; hh < 2; ++hh) {
      #pragma unroll
      for (int tt = 0; tt < 4; ++tt) {
        int t = hh * 4 + tt;
        unsigned w0, w1;
        asm("v_cvt_pk_bf16_f32 %0, %1, %2" : "=v"(w0) : "v"(s[t][0]), "v"(s[t][1]));
        asm("v_cvt_pk_bf16_f32 %0, %1, %2" : "=v"(w1) : "v"(s[t][2]), "v"(s[t][3]));
        *(uint2*)(prow + ((tt * 32 + g * 8) ^ sw)) = make_uint2(w0, w1);
      }
      asm volatile("s_waitcnt lgkmcnt(0)" ::: "memory");

      __builtin_amdgcn_s_setprio(1);
      #pragma unroll
      for (int kk = 0; kk < 2; ++kk) {
        int km = hh * 2 + kk;
        s16x8 pfrag = *(const s16x8_a*)(prow + ((kk * 64 + g * 16) ^ sw));
        O = __builtin_amdgcn_mfma_f32_16x16x32_bf16(vfr[km], pfrag, O, 0, 0, 0);
      }
      __builtin_amdgcn_s_setprio(0);
      asm volatile("" ::: "memory");   // keep next round's P writes behind these reads
    }
  }

  // l = row d=8 of O^T (lane 32+q, reg 0)
  float l = __shfl(O[0], 32 + q);

  // ---- merge the two key-halves via LDS
  if (half == 1) {
    if (g < 2) {
      #pragma unroll
      for (int r = 0; r < 4; ++r) obuf[qsub][q][g * 4 + r] = O[r];
    }
    if (lane < 16) { mbuf[qsub][lane] = m; lbuf[qsub][lane] = l; }
  }
  __syncthreads();
  if (half == 0 && g < 2) {
    float m2 = mbuf[qsub][q], l2 = lbuf[qsub][q];
    float mn = fmaxf(m, m2);
    float c1 = __builtin_amdgcn_exp2f(m - mn);
    float c2 = __builtin_amdgcn_exp2f(m2 - mn);
    float inv = 1.f / (l * c1 + l2 * c2);
    int qrow = qt * 64 + qsub * 16 + q;
    float* ap = aws + ((size_t)b * 64 + n * 8) * HW_;
    #pragma unroll
    for (int r = 0; r < 4; ++r)
      ap[(size_t)(g * 4 + r) * HW_ + qrow] = (O[r] * c1 + obuf[qsub][q][g * 4 + r] * c2) * inv;
  }
}

// ---------------- K3: 1x1 conv on attention map, ci halved across half-waves ----------------
// grid 512 = b(4) x ocq(16) x pt(8); 256 thr = 4 oc x [2 ci-halves x 32 p-quads]
__global__ __launch_bounds__(256) void k_attnconv(
    const float* __restrict__ aws, const float* __restrict__ w_attn, const float* __restrict__ b_attn,
    float* __restrict__ out)
{
  int bid = blockIdx.x;
  int pt  = bid & 7;
  int ocq = (bid >> 3) & 15;
  int b   = bid >> 7;
  int tid = threadIdx.x;
  int lane = tid & 63;
  int oc  = ocq * 4 + (tid >> 6);
  int hf  = lane >> 5;                 // ci half: 0 -> ci 0..31, 1 -> ci 32..63
  int p   = pt * 128 + (lane & 31) * 4;
  int ci0 = hf * 32;

  const float* wrow = w_attn + oc * 64 + ci0;
  const float* ab = aws + (size_t)b * 64 * HW_ + (size_t)ci0 * HW_ + p;
  float4 acc = make_float4(0.f, 0.f, 0.f, 0.f);
  #pragma unroll 16
  for (int ci = 0; ci < 32; ++ci) {
    float wv = wrow[ci];
    float4 a4 = *(const float4*)(ab + (size_t)ci * HW_);
    acc.x = fmaf(wv, a4.x, acc.x);
    acc.y = fmaf(wv, a4.y, acc.y);
    acc.z = fmaf(wv, a4.z, acc.z);
    acc.w = fmaf(wv, a4.w, acc.w);
  }
  acc.x += __shfl_xor(acc.x, 32);
  acc.y += __shfl_xor(acc.y, 32);
  acc.z += __shfl_xor(acc.z, 32);
  acc.w += __shfl_xor(acc.w, 32);
  if (hf == 0) {
    float bias = b_attn[oc];
    float4 r = make_float4(acc.x + bias, acc.y + bias, acc.z + bias, acc.w + bias);
    *(float4*)(out + ((size_t)b * 128 + 64 + oc) * HW_ + p) = r;
  }
}

extern "C" void kernel_launch(void* const* d_in, const int* in_sizes, int n_in,
                              void* d_out, int out_size, void* d_ws, size_t ws_size,
                              hipStream_t stream) {
  const float* x        = (const float*)d_in[0];
  const float* w_conv   = (const float*)d_in[1];
  const float* b_conv   = (const float*)d_in[2];
  const float* w_qkv    = (const float*)d_in[3];
  const float* b_qkv    = (const float*)d_in[4];
  const float* w_attn   = (const float*)d_in[5];
  const float* b_attn   = (const float*)d_in[6];
  const float* rel_h    = (const float*)d_in[7];
  const float* rel_w    = (const float*)d_in[8];
  float* out = (float*)d_out;

  float*  ws  = (float*)d_ws;
  float*  aws = ws;                               // [4][64][1024] f32 (1MB)
  ushort* qbf = (ushort*)(ws + 262144);           // [32][1024][8] bf16 (512KB)
  ushort* kbf = qbf + 262144;                     // [32][1024][8] bf16 (512KB)
  ushort* vtg = kbf + 262144;                     // [32][8][1024] bf16 (512KB)

  k_convs<<<512, 256, 0, stream>>>(x, w_conv, b_conv, w_qkv, b_qkv, out, qbf, kbf, vtg);
  k_attn<<<512, 512, 0, stream>>>(qbf, kbf, vtg, rel_h, rel_w, aws);
  k_attnconv<<<512, 256, 0, stream>>>(aws, w_attn, b_attn, out);
}

// Round 16
// 38.310 us; speedup vs baseline: 1.3675x; 1.3675x over previous
//
#include <hip/hip_runtime.h>
#include <math.h>

#define HW_ 1024

typedef __attribute__((ext_vector_type(4))) float   f32x4;
typedef __attribute__((ext_vector_type(8))) short   s16x8;

__device__ __forceinline__ unsigned bf16rne(float x) {
  unsigned u = __builtin_bit_cast(unsigned, x);
  u += 0x7FFF + ((u >> 16) & 1);
  return u >> 16;
}
__device__ __forceinline__ float bf2f(ushort u) {
  return __builtin_bit_cast(float, (unsigned)u << 16);
}

__device__ __forceinline__ void store_oc(int oc, const float av[4],
    float* __restrict__ out, ushort* __restrict__ qbf, ushort* __restrict__ kbf,
    ushort* __restrict__ vtg, int b, int p)
{
  if (oc < 64) {
    float4 acc = make_float4(av[0], av[1], av[2], av[3]);
    *(float4*)(out + ((size_t)b * 128 + oc) * HW_ + p) = acc;
  } else if (oc < 128) {
    const float SC = 0.35355339059327373f * 1.4426950408889634f;  // dkh^-0.5 * log2e
    int qc = oc - 64, n = qc >> 3, d = qc & 7, bn = b * 8 + n;
    #pragma unroll
    for (int i = 0; i < 4; ++i)
      qbf[((size_t)bn * HW_ + p + i) * 8 + d] = (ushort)bf16rne(av[i] * SC);
  } else if (oc < 192) {
    int kc = oc - 128, n = kc >> 3, d = kc & 7, bn = b * 8 + n;
    #pragma unroll
    for (int i = 0; i < 4; ++i)
      kbf[((size_t)bn * HW_ + p + i) * 8 + d] = (ushort)bf16rne(av[i]);
  } else {
    int vc = oc - 192, n = vc >> 3, d = vc & 7, bn = b * 8 + n;
    #pragma unroll
    for (int i = 0; i < 4; ++i)
      vtg[((size_t)bn * 8 + d) * HW_ + p + i] = (ushort)bf16rne(av[i]);
  }
}

// ---------------- K1: fused 1x1 convs, 2 oc/thread, ci halved across half-waves ----------------
// grid 1024 = b(4) x ocp(32) x pt(8); 256 thr = 4 ocg x [2 ci-halves x 32 p-quads]
__global__ __launch_bounds__(256) void k_convs(
    const float* __restrict__ x, const float* __restrict__ w_conv, const float* __restrict__ b_conv,
    const float* __restrict__ w_qkv, const float* __restrict__ b_qkv,
    float* __restrict__ out,
    ushort* __restrict__ qbf, ushort* __restrict__ kbf, ushort* __restrict__ vtg)
{
  int bid = blockIdx.x;
  int pt  = bid & 7;
  int ocp = (bid >> 3) & 31;
  int b   = bid >> 8;
  int tid = threadIdx.x;
  int lane = tid & 63;
  int oc0 = ocp * 8 + (tid >> 6) * 2;      // even; pair stays within one region
  int oc1 = oc0 + 1;
  int hf  = lane >> 5;                     // ci half: 0 -> ci 0..31, 1 -> 32..63
  int p   = pt * 128 + (lane & 31) * 4;
  int ci0 = hf * 32;

  const float* wrow0; const float* wrow1;
  float bias0, bias1;
  if (oc0 < 64) { wrow0 = w_conv + oc0 * 64 + ci0; bias0 = b_conv[oc0];
                  wrow1 = w_conv + oc1 * 64 + ci0; bias1 = b_conv[oc1]; }
  else          { wrow0 = w_qkv + (oc0 - 64) * 64 + ci0; bias0 = b_qkv[oc0 - 64];
                  wrow1 = w_qkv + (oc1 - 64) * 64 + ci0; bias1 = b_qkv[oc1 - 64]; }

  float4 a0 = make_float4(0.f, 0.f, 0.f, 0.f);
  float4 a1 = make_float4(0.f, 0.f, 0.f, 0.f);
  const float* xb = x + (size_t)b * 64 * HW_ + (size_t)ci0 * HW_ + p;
  #pragma unroll 16
  for (int ci = 0; ci < 32; ++ci) {
    float4 xv = *(const float4*)(xb + (size_t)ci * HW_);
    float w0 = wrow0[ci], w1 = wrow1[ci];
    a0.x = fmaf(w0, xv.x, a0.x); a1.x = fmaf(w1, xv.x, a1.x);
    a0.y = fmaf(w0, xv.y, a0.y); a1.y = fmaf(w1, xv.y, a1.y);
    a0.z = fmaf(w0, xv.z, a0.z); a1.z = fmaf(w1, xv.z, a1.z);
    a0.w = fmaf(w0, xv.w, a0.w); a1.w = fmaf(w1, xv.w, a1.w);
  }
  // combine ci halves across the wave split
  a0.x += __shfl_xor(a0.x, 32); a1.x += __shfl_xor(a1.x, 32);
  a0.y += __shfl_xor(a0.y, 32); a1.y += __shfl_xor(a1.y, 32);
  a0.z += __shfl_xor(a0.z, 32); a1.z += __shfl_xor(a1.z, 32);
  a0.w += __shfl_xor(a0.w, 32); a1.w += __shfl_xor(a1.w, 32);

  if (hf == 0) {
    float av0[4] = {a0.x + bias0, a0.y + bias0, a0.z + bias0, a0.w + bias0};
    float av1[4] = {a1.x + bias1, a1.y + bias1, a1.z + bias1, a1.w + bias1};
    store_oc(oc0, av0, out, qbf, kbf, vtg, b, p);
    store_oc(oc1, av1, out, qbf, kbf, vtg, b, p);
  }
}

// ---------------- K2: MFMA flash attention (R14-verbatim: K+V in LDS, bf16 rel tables) ----------------
// grid 512 = bn(32) x qt(16); 512 thr = 8 waves: qsub(4) x key-half(2)
// wave: 16 q-cols x 512 keys. S^T = mfma(K_lds, Q^T, C=rel); P via per-wave
// swizzled LDS; O^T = mfma(V_lds^T(+ones row), P^T, O); l rides in O row d=8.
__global__ __launch_bounds__(512, 4) void k_attn(
    const ushort* __restrict__ qbf, const ushort* __restrict__ kbf, const ushort* __restrict__ vtg,
    const float* __restrict__ rel_h, const float* __restrict__ rel_w,
    float* __restrict__ aws)
{
  __shared__ ushort rhd[64 * 36];        // bf16, stride 36 (8B-aligned rows of 4)
  __shared__ ushort rwd[64 * 36];
  __shared__ ushort P_lds[8][16][128];   // per-wave [q][key], 256B rows, XOR-swizzled
  __shared__ __align__(16) ushort K_lds[1024 * 8];  // whole head's K, [key][d], 16KB
  __shared__ __align__(16) ushort V_lds[1024 * 8];  // whole head's V^T, [d][key], swizzled, 16KB
  __shared__ float mbuf[4][16], lbuf[4][16];
  __shared__ float obuf[4][16][8];

  int bid = blockIdx.x;
  int qt = bid & 15;
  int bn = bid >> 4;
  int b = bn >> 3, n = bn & 7;
  int tid = threadIdx.x;
  int lane = tid & 63;
  int w = tid >> 6;
  int qsub = w & 3, half = w >> 2;

  // ---- stage K and V into LDS (coalesced global reads; V LDS-dst swizzled: unit ^= d&7)
  {
    const uint4* ksrc = (const uint4*)(kbf + (size_t)bn * HW_ * 8);
    const uint4* vsrc = (const uint4*)(vtg + (size_t)bn * 8 * HW_);
    uint4* kdst = (uint4*)K_lds;
    uint4* vdst = (uint4*)V_lds;
    kdst[tid]       = ksrc[tid];
    kdst[tid + 512] = ksrc[tid + 512];
    int g0 = tid, g1 = tid + 512;
    vdst[(g0 & ~127) | ((g0 & 127) ^ ((g0 >> 7) & 7))] = vsrc[g0];
    vdst[(g1 & ~127) | ((g1 & 127) ^ ((g1 >> 7) & 7))] = vsrc[g1];
  }

  // ---- build rel tables (bf16): rhd[qr][hp] = q.rel_h[hp-h+31], rwd[qr][wp] = q.rel_w[wp-w+31]
  {
    int qr = tid >> 3, qu = tid & 7;
    const ushort* qp = qbf + ((size_t)bn * HW_ + qt * 64 + qr) * 8;
    float qf[8];
    #pragma unroll
    for (int d = 0; d < 8; ++d) qf[d] = bf2f(qp[d]);
    int h = (qt * 64 + qr) >> 5, ww = qr & 31;
    #pragma unroll
    for (int s = 0; s < 4; ++s) {
      int idx = qu * 4 + s;
      const float* rp = rel_h + (idx - h + 31) * 8;
      float a = 0.f;
      #pragma unroll
      for (int d = 0; d < 8; ++d) a = fmaf(qf[d], rp[d], a);
      rhd[qr * 36 + idx] = (ushort)bf16rne(a);
      const float* rq = rel_w + (idx - ww + 31) * 8;
      float c = 0.f;
      #pragma unroll
      for (int d = 0; d < 8; ++d) c = fmaf(qf[d], rq[d], c);
      rwd[qr * 36 + idx] = (ushort)bf16rne(c);
    }
  }
  __syncthreads();

  int q = lane & 15, g = lane >> 4;
  int qr = qsub * 16 + q;

  s16x8 qfrag = {0,0,0,0,0,0,0,0};
  if (lane < 16)
    qfrag = *(const s16x8*)(qbf + ((size_t)bn * HW_ + qt * 64 + qsub * 16 + lane) * 8);

  float rw2[2][4];
  #pragma unroll
  for (int r = 0; r < 4; ++r) {
    rw2[0][r] = bf2f(rwd[qr * 36 + g * 4 + r]);
    rw2[1][r] = bf2f(rwd[qr * 36 + 16 + g * 4 + r]);
  }

  s16x8 vone;
  #pragma unroll
  for (int e = 0; e < 8; ++e) vone[e] = (short)0x3F80;   // bf16 1.0
  s16x8 vzero = {0,0,0,0,0,0,0,0};

  float m = -1e30f;
  f32x4 O = {0.f, 0.f, 0.f, 0.f};

  char* prow = (char*)&P_lds[w][0][0] + q * 256;
  int sw = (q & 7) << 4;

  #pragma unroll
  for (int bki = 0; bki < 4; ++bki) {
    int bk = half * 4 + bki;
    float rh4[4];
    #pragma unroll
    for (int j = 0; j < 4; ++j) rh4[j] = bf2f(rhd[qr * 36 + bk * 4 + j]);

    // ---- QK^T (S^T), rel logits as C-init; K from LDS
    f32x4 s[8];
    __builtin_amdgcn_s_setprio(1);
    #pragma unroll
    for (int t = 0; t < 8; ++t) {
      f32x4 c;
      #pragma unroll
      for (int r = 0; r < 4; ++r) c[r] = rh4[t >> 1] + rw2[t & 1][r];
      s16x8 kf = {0,0,0,0,0,0,0,0};
      if (lane < 16)
        kf = *(const s16x8*)(K_lds + (size_t)(bk * 128 + t * 16 + lane) * 8);
      s[t] = __builtin_amdgcn_mfma_f32_16x16x32_bf16(kf, qfrag, c, 0, 0, 0);
    }
    __builtin_amdgcn_s_setprio(0);

    // ---- V fragments from swizzled LDS
    s16x8 vfr[4];
    #pragma unroll
    for (int km = 0; km < 4; ++km) {
      if (q < 8)
        vfr[km] = *(const s16x8*)((const char*)V_lds + q * 2048 +
                                  (((bk * 16 + km * 4 + g) ^ q) << 4));
      else if (q == 8) vfr[km] = vone;
      else             vfr[km] = vzero;
    }

    // ---- online softmax max (base-2 domain)
    float t8[8];
    #pragma unroll
    for (int t = 0; t < 8; ++t)
      t8[t] = fmaxf(fmaxf(s[t][0], s[t][1]), fmaxf(s[t][2], s[t][3]));
    float mx = fmaxf(fmaxf(fmaxf(t8[0], t8[1]), fmaxf(t8[2], t8[3])),
                     fmaxf(fmaxf(t8[4], t8[5]), fmaxf(t8[6], t8[7])));
    mx = fmaxf(mx, __shfl_xor(mx, 16));
    mx = fmaxf(mx, __shfl_xor(mx, 32));
    float mn = fmaxf(m, mx);
    float corr = __builtin_amdgcn_exp2f(m - mn);
    m = mn;

    #pragma unroll
    for (int t = 0; t < 8; ++t)
      #pragma unroll
      for (int r = 0; r < 4; ++r)
        s[t][r] = __builtin_amdgcn_exp2f(s[t][r] - mn);

    #pragma unroll
    for (int r = 0; r < 4; ++r) O[r] *= corr;

    // ---- pack P (RNE via cvt_pk) into swizzled per-wave LDS
    #pragma unroll
    for (int t = 0; t < 8; ++t) {
      unsigned w0, w1;
      asm("v_cvt_pk_bf16_f32 %0, %1, %2" : "=v"(w0) : "v"(s[t][0]), "v"(s[t][1]));
      asm("v_cvt_pk_bf16_f32 %0, %1, %2" : "=v"(w1) : "v"(s[t][2]), "v"(s[t][3]));
      *(uint2*)(prow + (((t * 32 + g * 8) ^ sw))) = make_uint2(w0, w1);
    }
    asm volatile("s_waitcnt lgkmcnt(0)" ::: "memory");

    // ---- PV: O^T += [V^T; ones] . P^T
    __builtin_amdgcn_s_setprio(1);
    #pragma unroll
    for (int km = 0; km < 4; ++km) {
      s16x8 pfrag = *(const s16x8*)(prow + ((km * 64 + g * 16) ^ sw));
      O = __builtin_amdgcn_mfma_f32_16x16x32_bf16(vfr[km], pfrag, O, 0, 0, 0);
    }
    __builtin_amdgcn_s_setprio(0);
  }

  // l = row d=8 of O^T (lane 32+q, reg 0)
  float l = __shfl(O[0], 32 + q);

  // ---- merge the two key-halves via LDS
  if (half == 1) {
    if (g < 2) {
      #pragma unroll
      for (int r = 0; r < 4; ++r) obuf[qsub][q][g * 4 + r] = O[r];
    }
    if (lane < 16) { mbuf[qsub][lane] = m; lbuf[qsub][lane] = l; }
  }
  __syncthreads();
  if (half == 0 && g < 2) {
    float m2 = mbuf[qsub][q], l2 = lbuf[qsub][q];
    float mn = fmaxf(m, m2);
    float c1 = __builtin_amdgcn_exp2f(m - mn);
    float c2 = __builtin_amdgcn_exp2f(m2 - mn);
    float inv = 1.f / (l * c1 + l2 * c2);
    int qrow = qt * 64 + qsub * 16 + q;
    float* ap = aws + ((size_t)b * 64 + n * 8) * HW_;
    #pragma unroll
    for (int r = 0; r < 4; ++r)
      ap[(size_t)(g * 4 + r) * HW_ + qrow] = (O[r] * c1 + obuf[qsub][q][g * 4 + r] * c2) * inv;
  }
}

// ---------------- K3: 1x1 conv on attention map, ci halved across half-waves ----------------
// grid 512 = b(4) x ocq(16) x pt(8); 256 thr = 4 oc x [2 ci-halves x 32 p-quads]
__global__ __launch_bounds__(256) void k_attnconv(
    const float* __restrict__ aws, const float* __restrict__ w_attn, const float* __restrict__ b_attn,
    float* __restrict__ out)
{
  int bid = blockIdx.x;
  int pt  = bid & 7;
  int ocq = (bid >> 3) & 15;
  int b   = bid >> 7;
  int tid = threadIdx.x;
  int lane = tid & 63;
  int oc  = ocq * 4 + (tid >> 6);
  int hf  = lane >> 5;                 // ci half: 0 -> ci 0..31, 1 -> ci 32..63
  int p   = pt * 128 + (lane & 31) * 4;
  int ci0 = hf * 32;

  const float* wrow = w_attn + oc * 64 + ci0;
  const float* ab = aws + (size_t)b * 64 * HW_ + (size_t)ci0 * HW_ + p;
  float4 acc = make_float4(0.f, 0.f, 0.f, 0.f);
  #pragma unroll 16
  for (int ci = 0; ci < 32; ++ci) {
    float wv = wrow[ci];
    float4 a4 = *(const float4*)(ab + (size_t)ci * HW_);
    acc.x = fmaf(wv, a4.x, acc.x);
    acc.y = fmaf(wv, a4.y, acc.y);
    acc.z = fmaf(wv, a4.z, acc.z);
    acc.w = fmaf(wv, a4.w, acc.w);
  }
  acc.x += __shfl_xor(acc.x, 32);
  acc.y += __shfl_xor(acc.y, 32);
  acc.z += __shfl_xor(acc.z, 32);
  acc.w += __shfl_xor(acc.w, 32);
  if (hf == 0) {
    float bias = b_attn[oc];
    float4 r = make_float4(acc.x + bias, acc.y + bias, acc.z + bias, acc.w + bias);
    *(float4*)(out + ((size_t)b * 128 + 64 + oc) * HW_ + p) = r;
  }
}

extern "C" void kernel_launch(void* const* d_in, const int* in_sizes, int n_in,
                              void* d_out, int out_size, void* d_ws, size_t ws_size,
                              hipStream_t stream) {
  const float* x        = (const float*)d_in[0];
  const float* w_conv   = (const float*)d_in[1];
  const float* b_conv   = (const float*)d_in[2];
  const float* w_qkv    = (const float*)d_in[3];
  const float* b_qkv    = (const float*)d_in[4];
  const float* w_attn   = (const float*)d_in[5];
  const float* b_attn   = (const float*)d_in[6];
  const float* rel_h    = (const float*)d_in[7];
  const float* rel_w    = (const float*)d_in[8];
  float* out = (float*)d_out;

  float*  ws  = (float*)d_ws;
  float*  aws = ws;                               // [4][64][1024] f32 (1MB)
  ushort* qbf = (ushort*)(ws + 262144);           // [32][1024][8] bf16 (512KB)
  ushort* kbf = qbf + 262144;                     // [32][1024][8] bf16 (512KB)
  ushort* vtg = kbf + 262144;                     // [32][8][1024] bf16 (512KB)

  k_convs<<<1024, 256, 0, stream>>>(x, w_conv, b_conv, w_qkv, b_qkv, out, qbf, kbf, vtg);
  k_attn<<<512, 512, 0, stream>>>(qbf, kbf, vtg, rel_h, rel_w, aws);
  k_attnconv<<<512, 256, 0, stream>>>(aws, w_attn, b_attn, out);
}

// Round 17
// 35.917 us; speedup vs baseline: 1.4586x; 1.0666x over previous
//
#include <hip/hip_runtime.h>
#include <math.h>

#define HW_ 1024

typedef __attribute__((ext_vector_type(4))) float   f32x4;
typedef __attribute__((ext_vector_type(8))) short   s16x8;

__device__ __forceinline__ unsigned bf16rne(float x) {
  unsigned u = __builtin_bit_cast(unsigned, x);
  u += 0x7FFF + ((u >> 16) & 1);
  return u >> 16;
}
__device__ __forceinline__ float bf2f(ushort u) {
  return __builtin_bit_cast(float, (unsigned)u << 16);
}

__device__ __forceinline__ void store_oc(int oc, const float av[4],
    float* __restrict__ out, ushort* __restrict__ qbf, ushort* __restrict__ kbf,
    ushort* __restrict__ vtg, int b, int p)
{
  if (oc < 64) {
    float4 acc = make_float4(av[0], av[1], av[2], av[3]);
    *(float4*)(out + ((size_t)b * 128 + oc) * HW_ + p) = acc;
  } else if (oc < 128) {
    const float SC = 0.35355339059327373f * 1.4426950408889634f;  // dkh^-0.5 * log2e
    int qc = oc - 64, n = qc >> 3, d = qc & 7, bn = b * 8 + n;
    #pragma unroll
    for (int i = 0; i < 4; ++i)
      qbf[((size_t)bn * HW_ + p + i) * 8 + d] = (ushort)bf16rne(av[i] * SC);
  } else if (oc < 192) {
    int kc = oc - 128, n = kc >> 3, d = kc & 7, bn = b * 8 + n;
    #pragma unroll
    for (int i = 0; i < 4; ++i)
      kbf[((size_t)bn * HW_ + p + i) * 8 + d] = (ushort)bf16rne(av[i]);
  } else {
    int vc = oc - 192, n = vc >> 3, d = vc & 7, bn = b * 8 + n;
    #pragma unroll
    for (int i = 0; i < 4; ++i)
      vtg[((size_t)bn * 8 + d) * HW_ + p + i] = (ushort)bf16rne(av[i]);
  }
}

// ---------------- K1: fused 1x1 convs, 2 oc/thread, ci halved across half-waves ----------------
// grid 1024 = b(4) x ocp(32) x pt(8); 256 thr = 4 ocg x [2 ci-halves x 32 p-quads]
__global__ __launch_bounds__(256) void k_convs(
    const float* __restrict__ x, const float* __restrict__ w_conv, const float* __restrict__ b_conv,
    const float* __restrict__ w_qkv, const float* __restrict__ b_qkv,
    float* __restrict__ out,
    ushort* __restrict__ qbf, ushort* __restrict__ kbf, ushort* __restrict__ vtg)
{
  int bid = blockIdx.x;
  int pt  = bid & 7;
  int ocp = (bid >> 3) & 31;
  int b   = bid >> 8;
  int tid = threadIdx.x;
  int lane = tid & 63;
  int oc0 = ocp * 8 + (tid >> 6) * 2;      // even; pair stays within one region
  int oc1 = oc0 + 1;
  int hf  = lane >> 5;                     // ci half: 0 -> ci 0..31, 1 -> 32..63
  int p   = pt * 128 + (lane & 31) * 4;
  int ci0 = hf * 32;

  const float* wrow0; const float* wrow1;
  float bias0, bias1;
  if (oc0 < 64) { wrow0 = w_conv + oc0 * 64 + ci0; bias0 = b_conv[oc0];
                  wrow1 = w_conv + oc1 * 64 + ci0; bias1 = b_conv[oc1]; }
  else          { wrow0 = w_qkv + (oc0 - 64) * 64 + ci0; bias0 = b_qkv[oc0 - 64];
                  wrow1 = w_qkv + (oc1 - 64) * 64 + ci0; bias1 = b_qkv[oc1 - 64]; }

  float4 a0 = make_float4(0.f, 0.f, 0.f, 0.f);
  float4 a1 = make_float4(0.f, 0.f, 0.f, 0.f);
  const float* xb = x + (size_t)b * 64 * HW_ + (size_t)ci0 * HW_ + p;
  #pragma unroll 16
  for (int ci = 0; ci < 32; ++ci) {
    float4 xv = *(const float4*)(xb + (size_t)ci * HW_);
    float w0 = wrow0[ci], w1 = wrow1[ci];
    a0.x = fmaf(w0, xv.x, a0.x); a1.x = fmaf(w1, xv.x, a1.x);
    a0.y = fmaf(w0, xv.y, a0.y); a1.y = fmaf(w1, xv.y, a1.y);
    a0.z = fmaf(w0, xv.z, a0.z); a1.z = fmaf(w1, xv.z, a1.z);
    a0.w = fmaf(w0, xv.w, a0.w); a1.w = fmaf(w1, xv.w, a1.w);
  }
  // combine ci halves across the wave split
  a0.x += __shfl_xor(a0.x, 32); a1.x += __shfl_xor(a1.x, 32);
  a0.y += __shfl_xor(a0.y, 32); a1.y += __shfl_xor(a1.y, 32);
  a0.z += __shfl_xor(a0.z, 32); a1.z += __shfl_xor(a1.z, 32);
  a0.w += __shfl_xor(a0.w, 32); a1.w += __shfl_xor(a1.w, 32);

  if (hf == 0) {
    float av0[4] = {a0.x + bias0, a0.y + bias0, a0.z + bias0, a0.w + bias0};
    float av1[4] = {a1.x + bias1, a1.y + bias1, a1.z + bias1, a1.w + bias1};
    store_oc(oc0, av0, out, qbf, kbf, vtg, b, p);
    store_oc(oc1, av1, out, qbf, kbf, vtg, b, p);
  }
}

// ---------------- K2: MFMA flash attention (R16 minus online-max: fixed m=0) ----------------
// grid 512 = bn(32) x qt(16); 512 thr = 8 waves: qsub(4) x key-half(2)
// wave: 16 q-cols x 512 keys. S^T = mfma(K_lds, Q^T, C=rel); P = exp2(S) directly
// (|S| <= ~15 so no overflow; softmax normalization via l in ones-row d=8).
__global__ __launch_bounds__(512, 4) void k_attn(
    const ushort* __restrict__ qbf, const ushort* __restrict__ kbf, const ushort* __restrict__ vtg,
    const float* __restrict__ rel_h, const float* __restrict__ rel_w,
    float* __restrict__ aws)
{
  __shared__ ushort rhd[64 * 36];        // bf16, stride 36 (8B-aligned rows of 4)
  __shared__ ushort rwd[64 * 36];
  __shared__ ushort P_lds[8][16][128];   // per-wave [q][key], 256B rows, XOR-swizzled
  __shared__ __align__(16) ushort K_lds[1024 * 8];  // whole head's K, [key][d], 16KB
  __shared__ __align__(16) ushort V_lds[1024 * 8];  // whole head's V^T, [d][key], swizzled, 16KB
  __shared__ float lbuf[4][16];
  __shared__ float obuf[4][16][8];

  int bid = blockIdx.x;
  int qt = bid & 15;
  int bn = bid >> 4;
  int b = bn >> 3, n = bn & 7;
  int tid = threadIdx.x;
  int lane = tid & 63;
  int w = tid >> 6;
  int qsub = w & 3, half = w >> 2;

  // ---- stage K and V into LDS (coalesced global reads; V LDS-dst swizzled: unit ^= d&7)
  {
    const uint4* ksrc = (const uint4*)(kbf + (size_t)bn * HW_ * 8);
    const uint4* vsrc = (const uint4*)(vtg + (size_t)bn * 8 * HW_);
    uint4* kdst = (uint4*)K_lds;
    uint4* vdst = (uint4*)V_lds;
    kdst[tid]       = ksrc[tid];
    kdst[tid + 512] = ksrc[tid + 512];
    int g0 = tid, g1 = tid + 512;
    vdst[(g0 & ~127) | ((g0 & 127) ^ ((g0 >> 7) & 7))] = vsrc[g0];
    vdst[(g1 & ~127) | ((g1 & 127) ^ ((g1 >> 7) & 7))] = vsrc[g1];
  }

  // ---- build rel tables (bf16): rhd[qr][hp] = q.rel_h[hp-h+31], rwd[qr][wp] = q.rel_w[wp-w+31]
  {
    int qr = tid >> 3, qu = tid & 7;
    const ushort* qp = qbf + ((size_t)bn * HW_ + qt * 64 + qr) * 8;
    float qf[8];
    #pragma unroll
    for (int d = 0; d < 8; ++d) qf[d] = bf2f(qp[d]);
    int h = (qt * 64 + qr) >> 5, ww = qr & 31;
    #pragma unroll
    for (int s = 0; s < 4; ++s) {
      int idx = qu * 4 + s;
      const float* rp = rel_h + (idx - h + 31) * 8;
      float a = 0.f;
      #pragma unroll
      for (int d = 0; d < 8; ++d) a = fmaf(qf[d], rp[d], a);
      rhd[qr * 36 + idx] = (ushort)bf16rne(a);
      const float* rq = rel_w + (idx - ww + 31) * 8;
      float c = 0.f;
      #pragma unroll
      for (int d = 0; d < 8; ++d) c = fmaf(qf[d], rq[d], c);
      rwd[qr * 36 + idx] = (ushort)bf16rne(c);
    }
  }
  __syncthreads();

  int q = lane & 15, g = lane >> 4;
  int qr = qsub * 16 + q;

  s16x8 qfrag = {0,0,0,0,0,0,0,0};
  if (lane < 16)
    qfrag = *(const s16x8*)(qbf + ((size_t)bn * HW_ + qt * 64 + qsub * 16 + lane) * 8);

  float rw2[2][4];
  #pragma unroll
  for (int r = 0; r < 4; ++r) {
    rw2[0][r] = bf2f(rwd[qr * 36 + g * 4 + r]);
    rw2[1][r] = bf2f(rwd[qr * 36 + 16 + g * 4 + r]);
  }

  s16x8 vone;
  #pragma unroll
  for (int e = 0; e < 8; ++e) vone[e] = (short)0x3F80;   // bf16 1.0
  s16x8 vzero = {0,0,0,0,0,0,0,0};

  f32x4 O = {0.f, 0.f, 0.f, 0.f};

  char* prow = (char*)&P_lds[w][0][0] + q * 256;
  int sw = (q & 7) << 4;

  #pragma unroll
  for (int bki = 0; bki < 4; ++bki) {
    int bk = half * 4 + bki;
    float rh4[4];
    #pragma unroll
    for (int j = 0; j < 4; ++j) rh4[j] = bf2f(rhd[qr * 36 + bk * 4 + j]);

    // ---- QK^T (S^T), rel logits as C-init; K from LDS
    f32x4 s[8];
    __builtin_amdgcn_s_setprio(1);
    #pragma unroll
    for (int t = 0; t < 8; ++t) {
      f32x4 c;
      #pragma unroll
      for (int r = 0; r < 4; ++r) c[r] = rh4[t >> 1] + rw2[t & 1][r];
      s16x8 kf = {0,0,0,0,0,0,0,0};
      if (lane < 16)
        kf = *(const s16x8*)(K_lds + (size_t)(bk * 128 + t * 16 + lane) * 8);
      s[t] = __builtin_amdgcn_mfma_f32_16x16x32_bf16(kf, qfrag, c, 0, 0, 0);
    }
    __builtin_amdgcn_s_setprio(0);

    // ---- V fragments from swizzled LDS
    s16x8 vfr[4];
    #pragma unroll
    for (int km = 0; km < 4; ++km) {
      if (q < 8)
        vfr[km] = *(const s16x8*)((const char*)V_lds + q * 2048 +
                                  (((bk * 16 + km * 4 + g) ^ q) << 4));
      else if (q == 8) vfr[km] = vone;
      else             vfr[km] = vzero;
    }

    // ---- P = exp2(S) directly (no running max; |S| bounded ~15)
    #pragma unroll
    for (int t = 0; t < 8; ++t)
      #pragma unroll
      for (int r = 0; r < 4; ++r)
        s[t][r] = __builtin_amdgcn_exp2f(s[t][r]);

    // ---- pack P (RNE via cvt_pk) into swizzled per-wave LDS
    #pragma unroll
    for (int t = 0; t < 8; ++t) {
      unsigned w0, w1;
      asm("v_cvt_pk_bf16_f32 %0, %1, %2" : "=v"(w0) : "v"(s[t][0]), "v"(s[t][1]));
      asm("v_cvt_pk_bf16_f32 %0, %1, %2" : "=v"(w1) : "v"(s[t][2]), "v"(s[t][3]));
      *(uint2*)(prow + (((t * 32 + g * 8) ^ sw))) = make_uint2(w0, w1);
    }
    asm volatile("s_waitcnt lgkmcnt(0)" ::: "memory");

    // ---- PV: O^T += [V^T; ones] . P^T   (ones-row accumulates l in O row d=8)
    __builtin_amdgcn_s_setprio(1);
    #pragma unroll
    for (int km = 0; km < 4; ++km) {
      s16x8 pfrag = *(const s16x8*)(prow + ((km * 64 + g * 16) ^ sw));
      O = __builtin_amdgcn_mfma_f32_16x16x32_bf16(vfr[km], pfrag, O, 0, 0, 0);
    }
    __builtin_amdgcn_s_setprio(0);
  }

  // l = row d=8 of O^T (lane 32+q, reg 0)
  float l = __shfl(O[0], 32 + q);

  // ---- merge the two key-halves via LDS (plain sums; no max bookkeeping)
  if (half == 1) {
    if (g < 2) {
      #pragma unroll
      for (int r = 0; r < 4; ++r) obuf[qsub][q][g * 4 + r] = O[r];
    }
    if (lane < 16) lbuf[qsub][lane] = l;
  }
  __syncthreads();
  if (half == 0 && g < 2) {
    float inv = 1.f / (l + lbuf[qsub][q]);
    int qrow = qt * 64 + qsub * 16 + q;
    float* ap = aws + ((size_t)b * 64 + n * 8) * HW_;
    #pragma unroll
    for (int r = 0; r < 4; ++r)
      ap[(size_t)(g * 4 + r) * HW_ + qrow] = (O[r] + obuf[qsub][q][g * 4 + r]) * inv;
  }
}

// ---------------- K3: 1x1 conv on attention map, ci halved across half-waves ----------------
// grid 512 = b(4) x ocq(16) x pt(8); 256 thr = 4 oc x [2 ci-halves x 32 p-quads]
__global__ __launch_bounds__(256) void k_attnconv(
    const float* __restrict__ aws, const float* __restrict__ w_attn, const float* __restrict__ b_attn,
    float* __restrict__ out)
{
  int bid = blockIdx.x;
  int pt  = bid & 7;
  int ocq = (bid >> 3) & 15;
  int b   = bid >> 7;
  int tid = threadIdx.x;
  int lane = tid & 63;
  int oc  = ocq * 4 + (tid >> 6);
  int hf  = lane >> 5;                 // ci half: 0 -> ci 0..31, 1 -> ci 32..63
  int p   = pt * 128 + (lane & 31) * 4;
  int ci0 = hf * 32;

  const float* wrow = w_attn + oc * 64 + ci0;
  const float* ab = aws + (size_t)b * 64 * HW_ + (size_t)ci0 * HW_ + p;
  float4 acc = make_float4(0.f, 0.f, 0.f, 0.f);
  #pragma unroll 16
  for (int ci = 0; ci < 32; ++ci) {
    float wv = wrow[ci];
    float4 a4 = *(const float4*)(ab + (size_t)ci * HW_);
    acc.x = fmaf(wv, a4.x, acc.x);
    acc.y = fmaf(wv, a4.y, acc.y);
    acc.z = fmaf(wv, a4.z, acc.z);
    acc.w = fmaf(wv, a4.w, acc.w);
  }
  acc.x += __shfl_xor(acc.x, 32);
  acc.y += __shfl_xor(acc.y, 32);
  acc.z += __shfl_xor(acc.z, 32);
  acc.w += __shfl_xor(acc.w, 32);
  if (hf == 0) {
    float bias = b_attn[oc];
    float4 r = make_float4(acc.x + bias, acc.y + bias, acc.z + bias, acc.w + bias);
    *(float4*)(out + ((size_t)b * 128 + 64 + oc) * HW_ + p) = r;
  }
}

extern "C" void kernel_launch(void* const* d_in, const int* in_sizes, int n_in,
                              void* d_out, int out_size, void* d_ws, size_t ws_size,
                              hipStream_t stream) {
  const float* x        = (const float*)d_in[0];
  const float* w_conv   = (const float*)d_in[1];
  const float* b_conv   = (const float*)d_in[2];
  const float* w_qkv    = (const float*)d_in[3];
  const float* b_qkv    = (const float*)d_in[4];
  const float* w_attn   = (const float*)d_in[5];
  const float* b_attn   = (const float*)d_in[6];
  const float* rel_h    = (const float*)d_in[7];
  const float* rel_w    = (const float*)d_in[8];
  float* out = (float*)d_out;

  float*  ws  = (float*)d_ws;
  float*  aws = ws;                               // [4][64][1024] f32 (1MB)
  ushort* qbf = (ushort*)(ws + 262144);           // [32][1024][8] bf16 (512KB)
  ushort* kbf = qbf + 262144;                     // [32][1024][8] bf16 (512KB)
  ushort* vtg = kbf + 262144;                     // [32][8][1024] bf16 (512KB)

  k_convs<<<1024, 256, 0, stream>>>(x, w_conv, b_conv, w_qkv, b_qkv, out, qbf, kbf, vtg);
  k_attn<<<512, 512, 0, stream>>>(qbf, kbf, vtg, rel_h, rel_w, aws);
  k_attnconv<<<512, 256, 0, stream>>>(aws, w_attn, b_attn, out);
}

// Round 18
// 35.805 us; speedup vs baseline: 1.4631x; 1.0031x over previous
//
#include <hip/hip_runtime.h>
#include <math.h>

#define HW_ 1024

typedef __attribute__((ext_vector_type(4))) float   f32x4;
typedef __attribute__((ext_vector_type(8))) short   s16x8;

__device__ __forceinline__ unsigned bf16rne(float x) {
  unsigned u = __builtin_bit_cast(unsigned, x);
  u += 0x7FFF + ((u >> 16) & 1);
  return u >> 16;
}
__device__ __forceinline__ float bf2f(ushort u) {
  return __builtin_bit_cast(float, (unsigned)u << 16);
}

__device__ __forceinline__ void store_oc(int oc, const float av[4],
    float* __restrict__ out, ushort* __restrict__ qbf, ushort* __restrict__ kbf,
    ushort* __restrict__ vtg, int b, int p)
{
  if (oc < 64) {
    float4 acc = make_float4(av[0], av[1], av[2], av[3]);
    *(float4*)(out + ((size_t)b * 128 + oc) * HW_ + p) = acc;
  } else if (oc < 128) {
    const float SC = 0.35355339059327373f * 1.4426950408889634f;  // dkh^-0.5 * log2e
    int qc = oc - 64, n = qc >> 3, d = qc & 7, bn = b * 8 + n;
    #pragma unroll
    for (int i = 0; i < 4; ++i)
      qbf[((size_t)bn * HW_ + p + i) * 8 + d] = (ushort)bf16rne(av[i] * SC);
  } else if (oc < 192) {
    int kc = oc - 128, n = kc >> 3, d = kc & 7, bn = b * 8 + n;
    #pragma unroll
    for (int i = 0; i < 4; ++i)
      kbf[((size_t)bn * HW_ + p + i) * 8 + d] = (ushort)bf16rne(av[i]);
  } else {
    int vc = oc - 192, n = vc >> 3, d = vc & 7, bn = b * 8 + n;
    #pragma unroll
    for (int i = 0; i < 4; ++i)
      vtg[((size_t)bn * 8 + d) * HW_ + p + i] = (ushort)bf16rne(av[i]);
  }
}

// ---------------- K1: fused 1x1 convs, 2 oc/thread, ci halved across half-waves ----------------
// grid 1024 = b(4) x ocp(32) x pt(8); 256 thr = 4 ocg x [2 ci-halves x 32 p-quads]
__global__ __launch_bounds__(256) void k_convs(
    const float* __restrict__ x, const float* __restrict__ w_conv, const float* __restrict__ b_conv,
    const float* __restrict__ w_qkv, const float* __restrict__ b_qkv,
    float* __restrict__ out,
    ushort* __restrict__ qbf, ushort* __restrict__ kbf, ushort* __restrict__ vtg)
{
  int bid = blockIdx.x;
  int pt  = bid & 7;
  int ocp = (bid >> 3) & 31;
  int b   = bid >> 8;
  int tid = threadIdx.x;
  int lane = tid & 63;
  int oc0 = ocp * 8 + (tid >> 6) * 2;      // even; pair stays within one region
  int oc1 = oc0 + 1;
  int hf  = lane >> 5;                     // ci half: 0 -> ci 0..31, 1 -> 32..63
  int p   = pt * 128 + (lane & 31) * 4;
  int ci0 = hf * 32;

  const float* wrow0; const float* wrow1;
  float bias0, bias1;
  if (oc0 < 64) { wrow0 = w_conv + oc0 * 64 + ci0; bias0 = b_conv[oc0];
                  wrow1 = w_conv + oc1 * 64 + ci0; bias1 = b_conv[oc1]; }
  else          { wrow0 = w_qkv + (oc0 - 64) * 64 + ci0; bias0 = b_qkv[oc0 - 64];
                  wrow1 = w_qkv + (oc1 - 64) * 64 + ci0; bias1 = b_qkv[oc1 - 64]; }

  float4 a0 = make_float4(0.f, 0.f, 0.f, 0.f);
  float4 a1 = make_float4(0.f, 0.f, 0.f, 0.f);
  const float* xb = x + (size_t)b * 64 * HW_ + (size_t)ci0 * HW_ + p;
  #pragma unroll 16
  for (int ci = 0; ci < 32; ++ci) {
    float4 xv = *(const float4*)(xb + (size_t)ci * HW_);
    float w0 = wrow0[ci], w1 = wrow1[ci];
    a0.x = fmaf(w0, xv.x, a0.x); a1.x = fmaf(w1, xv.x, a1.x);
    a0.y = fmaf(w0, xv.y, a0.y); a1.y = fmaf(w1, xv.y, a1.y);
    a0.z = fmaf(w0, xv.z, a0.z); a1.z = fmaf(w1, xv.z, a1.z);
    a0.w = fmaf(w0, xv.w, a0.w); a1.w = fmaf(w1, xv.w, a1.w);
  }
  // combine ci halves across the wave split
  a0.x += __shfl_xor(a0.x, 32); a1.x += __shfl_xor(a1.x, 32);
  a0.y += __shfl_xor(a0.y, 32); a1.y += __shfl_xor(a1.y, 32);
  a0.z += __shfl_xor(a0.z, 32); a1.z += __shfl_xor(a1.z, 32);
  a0.w += __shfl_xor(a0.w, 32); a1.w += __shfl_xor(a1.w, 32);

  if (hf == 0) {
    float av0[4] = {a0.x + bias0, a0.y + bias0, a0.z + bias0, a0.w + bias0};
    float av1[4] = {a1.x + bias1, a1.y + bias1, a1.z + bias1, a1.w + bias1};
    store_oc(oc0, av0, out, qbf, kbf, vtg, b, p);
    store_oc(oc1, av1, out, qbf, kbf, vtg, b, p);
  }
}

// ---------------- K2: MFMA flash attention (R17 + zero-inst LDS ordering barrier) ----------------
// grid 512 = bn(32) x qt(16); 512 thr = 8 waves: qsub(4) x key-half(2)
// wave: 16 q-cols x 512 keys. S^T = mfma(K_lds, Q^T, C=rel); P = exp2(S) directly;
// P write->read ordering relies on HW in-order DS per wave + compiler barrier.
__global__ __launch_bounds__(512, 4) void k_attn(
    const ushort* __restrict__ qbf, const ushort* __restrict__ kbf, const ushort* __restrict__ vtg,
    const float* __restrict__ rel_h, const float* __restrict__ rel_w,
    float* __restrict__ aws)
{
  __shared__ ushort rhd[64 * 36];        // bf16, stride 36 (8B-aligned rows of 4)
  __shared__ ushort rwd[64 * 36];
  __shared__ ushort P_lds[8][16][128];   // per-wave [q][key], 256B rows, XOR-swizzled
  __shared__ __align__(16) ushort K_lds[1024 * 8];  // whole head's K, [key][d], 16KB
  __shared__ __align__(16) ushort V_lds[1024 * 8];  // whole head's V^T, [d][key], swizzled, 16KB
  __shared__ float lbuf[4][16];
  __shared__ float obuf[4][16][8];

  int bid = blockIdx.x;
  int qt = bid & 15;
  int bn = bid >> 4;
  int b = bn >> 3, n = bn & 7;
  int tid = threadIdx.x;
  int lane = tid & 63;
  int w = tid >> 6;
  int qsub = w & 3, half = w >> 2;

  // ---- stage K and V into LDS (coalesced global reads; V LDS-dst swizzled: unit ^= d&7)
  {
    const uint4* ksrc = (const uint4*)(kbf + (size_t)bn * HW_ * 8);
    const uint4* vsrc = (const uint4*)(vtg + (size_t)bn * 8 * HW_);
    uint4* kdst = (uint4*)K_lds;
    uint4* vdst = (uint4*)V_lds;
    kdst[tid]       = ksrc[tid];
    kdst[tid + 512] = ksrc[tid + 512];
    int g0 = tid, g1 = tid + 512;
    vdst[(g0 & ~127) | ((g0 & 127) ^ ((g0 >> 7) & 7))] = vsrc[g0];
    vdst[(g1 & ~127) | ((g1 & 127) ^ ((g1 >> 7) & 7))] = vsrc[g1];
  }

  // ---- build rel tables (bf16): rhd[qr][hp] = q.rel_h[hp-h+31], rwd[qr][wp] = q.rel_w[wp-w+31]
  {
    int qr = tid >> 3, qu = tid & 7;
    const ushort* qp = qbf + ((size_t)bn * HW_ + qt * 64 + qr) * 8;
    float qf[8];
    #pragma unroll
    for (int d = 0; d < 8; ++d) qf[d] = bf2f(qp[d]);
    int h = (qt * 64 + qr) >> 5, ww = qr & 31;
    #pragma unroll
    for (int s = 0; s < 4; ++s) {
      int idx = qu * 4 + s;
      const float* rp = rel_h + (idx - h + 31) * 8;
      float a = 0.f;
      #pragma unroll
      for (int d = 0; d < 8; ++d) a = fmaf(qf[d], rp[d], a);
      rhd[qr * 36 + idx] = (ushort)bf16rne(a);
      const float* rq = rel_w + (idx - ww + 31) * 8;
      float c = 0.f;
      #pragma unroll
      for (int d = 0; d < 8; ++d) c = fmaf(qf[d], rq[d], c);
      rwd[qr * 36 + idx] = (ushort)bf16rne(c);
    }
  }
  __syncthreads();

  int q = lane & 15, g = lane >> 4;
  int qr = qsub * 16 + q;

  s16x8 qfrag = {0,0,0,0,0,0,0,0};
  if (lane < 16)
    qfrag = *(const s16x8*)(qbf + ((size_t)bn * HW_ + qt * 64 + qsub * 16 + lane) * 8);

  float rw2[2][4];
  #pragma unroll
  for (int r = 0; r < 4; ++r) {
    rw2[0][r] = bf2f(rwd[qr * 36 + g * 4 + r]);
    rw2[1][r] = bf2f(rwd[qr * 36 + 16 + g * 4 + r]);
  }

  s16x8 vone;
  #pragma unroll
  for (int e = 0; e < 8; ++e) vone[e] = (short)0x3F80;   // bf16 1.0
  s16x8 vzero = {0,0,0,0,0,0,0,0};

  f32x4 O = {0.f, 0.f, 0.f, 0.f};

  char* prow = (char*)&P_lds[w][0][0] + q * 256;
  int sw = (q & 7) << 4;

  #pragma unroll
  for (int bki = 0; bki < 4; ++bki) {
    int bk = half * 4 + bki;
    float rh4[4];
    #pragma unroll
    for (int j = 0; j < 4; ++j) rh4[j] = bf2f(rhd[qr * 36 + bk * 4 + j]);

    // ---- QK^T (S^T), rel logits as C-init; K from LDS
    f32x4 s[8];
    __builtin_amdgcn_s_setprio(1);
    #pragma unroll
    for (int t = 0; t < 8; ++t) {
      f32x4 c;
      #pragma unroll
      for (int r = 0; r < 4; ++r) c[r] = rh4[t >> 1] + rw2[t & 1][r];
      s16x8 kf = {0,0,0,0,0,0,0,0};
      if (lane < 16)
        kf = *(const s16x8*)(K_lds + (size_t)(bk * 128 + t * 16 + lane) * 8);
      s[t] = __builtin_amdgcn_mfma_f32_16x16x32_bf16(kf, qfrag, c, 0, 0, 0);
    }
    __builtin_amdgcn_s_setprio(0);

    // ---- V fragments from swizzled LDS
    s16x8 vfr[4];
    #pragma unroll
    for (int km = 0; km < 4; ++km) {
      if (q < 8)
        vfr[km] = *(const s16x8*)((const char*)V_lds + q * 2048 +
                                  (((bk * 16 + km * 4 + g) ^ q) << 4));
      else if (q == 8) vfr[km] = vone;
      else             vfr[km] = vzero;
    }

    // ---- P = exp2(S) directly (no running max; |S| bounded ~15)
    #pragma unroll
    for (int t = 0; t < 8; ++t)
      #pragma unroll
      for (int r = 0; r < 4; ++r)
        s[t][r] = __builtin_amdgcn_exp2f(s[t][r]);

    // ---- pack P (RNE via cvt_pk) into swizzled per-wave LDS
    #pragma unroll
    for (int t = 0; t < 8; ++t) {
      unsigned w0, w1;
      asm("v_cvt_pk_bf16_f32 %0, %1, %2" : "=v"(w0) : "v"(s[t][0]), "v"(s[t][1]));
      asm("v_cvt_pk_bf16_f32 %0, %1, %2" : "=v"(w1) : "v"(s[t][2]), "v"(s[t][3]));
      *(uint2*)(prow + (((t * 32 + g * 8) ^ sw))) = make_uint2(w0, w1);
    }
    // compiler-only ordering barrier: DS ops from one wave complete in order,
    // so the ds_reads below observe the ds_writes above without a waitcnt.
    asm volatile("" ::: "memory");

    // ---- PV: O^T += [V^T; ones] . P^T   (ones-row accumulates l in O row d=8)
    __builtin_amdgcn_s_setprio(1);
    #pragma unroll
    for (int km = 0; km < 4; ++km) {
      s16x8 pfrag = *(const s16x8*)(prow + ((km * 64 + g * 16) ^ sw));
      O = __builtin_amdgcn_mfma_f32_16x16x32_bf16(vfr[km], pfrag, O, 0, 0, 0);
    }
    __builtin_amdgcn_s_setprio(0);
    // keep next iteration's P writes behind this iteration's reads
    asm volatile("" ::: "memory");
  }

  // l = row d=8 of O^T (lane 32+q, reg 0)
  float l = __shfl(O[0], 32 + q);

  // ---- merge the two key-halves via LDS (plain sums; no max bookkeeping)
  if (half == 1) {
    if (g < 2) {
      #pragma unroll
      for (int r = 0; r < 4; ++r) obuf[qsub][q][g * 4 + r] = O[r];
    }
    if (lane < 16) lbuf[qsub][lane] = l;
  }
  __syncthreads();
  if (half == 0 && g < 2) {
    float inv = 1.f / (l + lbuf[qsub][q]);
    int qrow = qt * 64 + qsub * 16 + q;
    float* ap = aws + ((size_t)b * 64 + n * 8) * HW_;
    #pragma unroll
    for (int r = 0; r < 4; ++r)
      ap[(size_t)(g * 4 + r) * HW_ + qrow] = (O[r] + obuf[qsub][q][g * 4 + r]) * inv;
  }
}

// ---------------- K3: 1x1 conv on attention map, ci halved across half-waves ----------------
// grid 512 = b(4) x ocq(16) x pt(8); 256 thr = 4 oc x [2 ci-halves x 32 p-quads]
__global__ __launch_bounds__(256) void k_attnconv(
    const float* __restrict__ aws, const float* __restrict__ w_attn, const float* __restrict__ b_attn,
    float* __restrict__ out)
{
  int bid = blockIdx.x;
  int pt  = bid & 7;
  int ocq = (bid >> 3) & 15;
  int b   = bid >> 7;
  int tid = threadIdx.x;
  int lane = tid & 63;
  int oc  = ocq * 4 + (tid >> 6);
  int hf  = lane >> 5;                 // ci half: 0 -> ci 0..31, 1 -> ci 32..63
  int p   = pt * 128 + (lane & 31) * 4;
  int ci0 = hf * 32;

  const float* wrow = w_attn + oc * 64 + ci0;
  const float* ab = aws + (size_t)b * 64 * HW_ + (size_t)ci0 * HW_ + p;
  float4 acc = make_float4(0.f, 0.f, 0.f, 0.f);
  #pragma unroll 16
  for (int ci = 0; ci < 32; ++ci) {
    float wv = wrow[ci];
    float4 a4 = *(const float4*)(ab + (size_t)ci * HW_);
    acc.x = fmaf(wv, a4.x, acc.x);
    acc.y = fmaf(wv, a4.y, acc.y);
    acc.z = fmaf(wv, a4.z, acc.z);
    acc.w = fmaf(wv, a4.w, acc.w);
  }
  acc.x += __shfl_xor(acc.x, 32);
  acc.y += __shfl_xor(acc.y, 32);
  acc.z += __shfl_xor(acc.z, 32);
  acc.w += __shfl_xor(acc.w, 32);
  if (hf == 0) {
    float bias = b_attn[oc];
    float4 r = make_float4(acc.x + bias, acc.y + bias, acc.z + bias, acc.w + bias);
    *(float4*)(out + ((size_t)b * 128 + 64 + oc) * HW_ + p) = r;
  }
}

extern "C" void kernel_launch(void* const* d_in, const int* in_sizes, int n_in,
                              void* d_out, int out_size, void* d_ws, size_t ws_size,
                              hipStream_t stream) {
  const float* x        = (const float*)d_in[0];
  const float* w_conv   = (const float*)d_in[1];
  const float* b_conv   = (const float*)d_in[2];
  const float* w_qkv    = (const float*)d_in[3];
  const float* b_qkv    = (const float*)d_in[4];
  const float* w_attn   = (const float*)d_in[5];
  const float* b_attn   = (const float*)d_in[6];
  const float* rel_h    = (const float*)d_in[7];
  const float* rel_w    = (const float*)d_in[8];
  float* out = (float*)d_out;

  float*  ws  = (float*)d_ws;
  float*  aws = ws;                               // [4][64][1024] f32 (1MB)
  ushort* qbf = (ushort*)(ws + 262144);           // [32][1024][8] bf16 (512KB)
  ushort* kbf = qbf + 262144;                     // [32][1024][8] bf16 (512KB)
  ushort* vtg = kbf + 262144;                     // [32][8][1024] bf16 (512KB)

  k_convs<<<1024, 256, 0, stream>>>(x, w_conv, b_conv, w_qkv, b_qkv, out, qbf, kbf, vtg);
  k_attn<<<512, 512, 0, stream>>>(qbf, kbf, vtg, rel_h, rel_w, aws);
  k_attnconv<<<512, 256, 0, stream>>>(aws, w_attn, b_attn, out);
}